// Round 1
// baseline (330.690 us; speedup 1.0000x reference)
//
#include <hip/hip_runtime.h>

// sample_pdf (NeRF hierarchical sampling), fp32.
// bins: [N, 64] sorted edges; weights: [N, 63]; u: [N, 128] in [0,1).
// out[n,i] = inverse-CDF sample of u[n,i] against pdf built from weights[n,:].
//
// One wave64 per ray; 4 rays per 256-thread block. Memory-bound:
// ~401 MB total traffic -> ~64 us floor at 6.3 TB/s.

constexpr int NBINS = 64;        // bin edges per ray
constexpr int NW = NBINS - 1;    // weights per ray
constexpr int NIMP = 128;        // importance samples per ray
constexpr int RAYS_PER_BLOCK = 4;

__global__ __launch_bounds__(256) void sample_pdf_kernel(
    const float* __restrict__ bins,
    const float* __restrict__ weights,
    const float* __restrict__ u,
    float* __restrict__ out,
    int n_rays)
{
    __shared__ float s_cdf[RAYS_PER_BLOCK][NBINS];
    __shared__ float s_bins[RAYS_PER_BLOCK][NBINS];

    const int wave = threadIdx.x >> 6;   // 0..3, one ray per wave
    const int lane = threadIdx.x & 63;
    int ray = blockIdx.x * RAYS_PER_BLOCK + wave;
    if (ray >= n_rays) ray = n_rays - 1; // tail: duplicate work, identical writes (benign)

    // ---- stage bins into LDS (coalesced: 64 lanes x 4B contiguous) ----
    s_bins[wave][lane] = bins[(size_t)ray * NBINS + lane];

    // ---- weights -> wave-wide inclusive scan -> normalized cdf ----
    float v = (lane < NW) ? (weights[(size_t)ray * NW + lane] + 1e-5f) : 0.0f;
    #pragma unroll
    for (int off = 1; off < 64; off <<= 1) {
        const float n = __shfl_up(v, off, 64);
        if (lane >= off) v += n;
    }
    const float T = __shfl(v, NW - 1, 64);   // total weight = S_62 (> 63e-5 > 0)
    if (lane < NW) s_cdf[wave][lane + 1] = v / T;  // cdf[63] == 1.0 exactly
    if (lane == 0) s_cdf[wave][0] = 0.0f;

    __syncthreads();  // make LDS writes visible (cross-lane dep the compiler can't see)

    const float* __restrict__ cdf = s_cdf[wave];
    const float* __restrict__ bn  = s_bins[wave];

    // ---- 2 samples per lane: coalesced float2 load of u ----
    const float2 uu = ((const float2*)(u + (size_t)ray * NIMP))[lane];
    float2 res;

    #pragma unroll
    for (int k = 0; k < 2; ++k) {
        const float uv = (k == 0) ? uu.x : uu.y;

        // Branchless lower_bound over cdf[0..63] (size 64 = 2^6).
        // Finds largest pos with cdf[pos] < uv; pos+s never exceeds 63.
        int pos = 0;
        #pragma unroll
        for (int s = 32; s > 0; s >>= 1) {
            const int np = pos + s;
            if (cdf[np] < uv) pos = np;
        }
        // idx = searchsorted(cdf, uv, side='left') = #elements < uv
        const int idx   = (cdf[0] < uv) ? pos + 1 : 0;
        const int lower = (idx > 0) ? idx - 1 : 0;
        const int upper = (idx < NBINS - 1) ? idx : NBINS - 1;

        const float clo = cdf[lower], chi = cdf[upper];
        const float blo = bn[lower],  bhi = bn[upper];
        float denom = chi - clo;
        denom = (denom < 1e-5f) ? 1.0f : denom;
        const float t  = (uv - clo) / denom;
        const float sm = blo + t * (bhi - blo);
        if (k == 0) res.x = sm; else res.y = sm;
    }

    ((float2*)(out + (size_t)ray * NIMP))[lane] = res;
}

extern "C" void kernel_launch(void* const* d_in, const int* in_sizes, int n_in,
                              void* d_out, int out_size, void* d_ws, size_t ws_size,
                              hipStream_t stream) {
    const float* bins    = (const float*)d_in[0];
    const float* weights = (const float*)d_in[1];
    const float* u       = (const float*)d_in[2];
    // d_in[3] = n_importance scalar (always 128 here); layout baked into constants.
    float* out = (float*)d_out;

    const int n_rays = in_sizes[0] / NBINS;
    const int grid = (n_rays + RAYS_PER_BLOCK - 1) / RAYS_PER_BLOCK;
    sample_pdf_kernel<<<grid, 256, 0, stream>>>(bins, weights, u, out, n_rays);
}

// Round 2
// 325.251 us; speedup vs baseline: 1.0167x; 1.0167x over previous
//
#include <hip/hip_runtime.h>

// sample_pdf (NeRF hierarchical sampling), fp32.
// bins: [N, 64] sorted edges; weights: [N, 63]; u: [N, 128] -> out [N, 128].
//
// One wave64 per ray; 4 rays per 256-thread block.
// R1 post-mortem: LDS-pipe bound (~28 DS ops/wave + 9.4M conflict cycles).
// R2: DPP scan (0 DS), 3 register search levels via readlane (scalar bcast),
//     lo-tracking kills the cdf[lower] gather, no __syncthreads (wave-private LDS).
//     DS/wave: 28 -> 14.

constexpr int NBINS = 64;
constexpr int NW = NBINS - 1;
constexpr int NIMP = 128;
constexpr int RAYS_PER_BLOCK = 4;

template <int Ctrl, int Rm>
__device__ __forceinline__ float dppterm(float x) {
    // update_dpp(old=0,...): lanes with invalid source (bound_ctrl) or masked-off
    // rows (row_mask) produce 0, so "x += dppterm(x)" is the identity there.
    return __int_as_float(__builtin_amdgcn_update_dpp(
        0, __float_as_int(x), Ctrl, Rm, 0xF, true));
}

__device__ __forceinline__ float rdlane(float x, int lane) {
    return __int_as_float(__builtin_amdgcn_readlane(__float_as_int(x), lane));
}

// wave64 inclusive scan, pure VALU (DPP), no DS ops
__device__ __forceinline__ float wave_incl_scan(float x) {
    x += dppterm<0x111, 0xF>(x);  // row_shr:1
    x += dppterm<0x112, 0xF>(x);  // row_shr:2
    x += dppterm<0x114, 0xF>(x);  // row_shr:4
    x += dppterm<0x118, 0xF>(x);  // row_shr:8  -> per-16 row scans
    x += dppterm<0x142, 0xA>(x);  // row_bcast:15 -> rows 1,3 get row 0/2 totals
    x += dppterm<0x143, 0xC>(x);  // row_bcast:31 -> lanes 32..63 get total(0..31)
    return x;
}

__global__ __launch_bounds__(256) void sample_pdf_kernel(
    const float* __restrict__ bins,
    const float* __restrict__ weights,
    const float* __restrict__ u,
    float* __restrict__ out,
    int n_rays)
{
    __shared__ float s_cdf[RAYS_PER_BLOCK][NBINS];
    __shared__ float s_bins[RAYS_PER_BLOCK][NBINS];

    const int wave = threadIdx.x >> 6;
    const int lane = threadIdx.x & 63;
    int ray = blockIdx.x * RAYS_PER_BLOCK + wave;
    if (ray >= n_rays) ray = n_rays - 1;  // tail: duplicated work, identical writes

    // stage bins (coalesced 256 B/wave)
    const float bv = bins[(size_t)ray * NBINS + lane];
    s_bins[wave][lane] = bv;

    // weights + 1e-5 -> inclusive scan -> normalized cdf (divide-after, as R1)
    const float w = (lane < NW) ? (weights[(size_t)ray * NW + lane] + 1e-5f) : 0.0f;
    const float S = wave_incl_scan(w);
    const float T = rdlane(S, NW - 1);     // total = S[62] > 0
    const float cdfv = S / T;              // cdf[lane+1]; lane62 -> exactly 1.0

    if (lane < NW) s_cdf[wave][lane + 1] = cdfv;
    if (lane == NW) s_cdf[wave][0] = 0.0f;   // lane 63 writes cdf[0]
    // No __syncthreads: each wave only touches its own LDS slice; the same-wave
    // write->read ordering is enforced by compiler-inserted lgkmcnt waits.

    // broadcast search pivots: cdf[8k] = cdfv@lane(8k-1), k=1..7 (scalar regs)
    const float c8  = rdlane(cdfv, 7);
    const float c16 = rdlane(cdfv, 15);
    const float c24 = rdlane(cdfv, 23);
    const float c32 = rdlane(cdfv, 31);
    const float c40 = rdlane(cdfv, 39);
    const float c48 = rdlane(cdfv, 47);
    const float c56 = rdlane(cdfv, 55);

    const float* __restrict__ cdf = s_cdf[wave];
    const float* __restrict__ bn  = s_bins[wave];

    const float2 uu = ((const float2*)(u + (size_t)ray * NIMP))[lane];
    float2 res;

    #pragma unroll
    for (int k = 0; k < 2; ++k) {
        const float uv = (k == 0) ? uu.x : uu.y;

        // lower_bound: largest pos with cdf[pos] < uv (pos=0 if none).
        // Track lo = cdf[pos] so cdf[lower] needs no LDS gather.
        int pos = 0;
        float lo = 0.0f;
        const bool b1 = (c32 < uv);
        if (b1) { pos = 32; lo = c32; }
        const float m2 = b1 ? c48 : c16;
        const bool b2 = (m2 < uv);
        if (b2) { pos += 16; lo = m2; }
        const float m3 = b2 ? (b1 ? c56 : c24) : (b1 ? c40 : c8);
        const bool b3 = (m3 < uv);
        if (b3) { pos += 8; lo = m3; }

        #pragma unroll
        for (int s = 4; s >= 1; s >>= 1) {          // 3 LDS steps, broadcast addrs
            const float val = cdf[pos + s];
            if (val < uv) { pos += s; lo = val; }
        }

        // idx = pos+1 if uv>0 else 0; lower = pos in both cases; upper = min(idx,63)
        const int upper = (uv > 0.0f) ? (pos + 1) : 0;  // pos<=62 since cdf[63]=1>uv
        const float chi = cdf[upper];
        const float blo = bn[pos];
        const float bhi = bn[upper];

        float denom = chi - lo;
        denom = (denom < 1e-5f) ? 1.0f : denom;
        const float t = (uv - lo) / denom;
        const float sm = blo + t * (bhi - blo);
        if (k == 0) res.x = sm; else res.y = sm;
    }

    ((float2*)(out + (size_t)ray * NIMP))[lane] = res;
}

extern "C" void kernel_launch(void* const* d_in, const int* in_sizes, int n_in,
                              void* d_out, int out_size, void* d_ws, size_t ws_size,
                              hipStream_t stream) {
    const float* bins    = (const float*)d_in[0];
    const float* weights = (const float*)d_in[1];
    const float* u       = (const float*)d_in[2];
    float* out = (float*)d_out;

    const int n_rays = in_sizes[0] / NBINS;
    const int grid = (n_rays + RAYS_PER_BLOCK - 1) / RAYS_PER_BLOCK;
    sample_pdf_kernel<<<grid, 256, 0, stream>>>(bins, weights, u, out, n_rays);
}